// Round 1
// baseline (119.859 us; speedup 1.0000x reference)
//
#include <hip/hip_runtime.h>
#include <math.h>

// Chamfer distance: pred (4,8192,3) fp32, gt (4,8192,3) fp32 -> scalar fp32.
// Strategy: pack clouds as float4(x,y,z,|p|^2); dist = s_q + (s_g - 2 q.g);
// per-pair inner = 3 fma + 1 min. Query-minima combined across target-chunks
// via uint atomicMin on non-negative float bits.

#define NPTS   8192
#define NB     4
#define TOTAL  (NB * NPTS)        // 32768 points per cloud
#define TT     1024               // target points staged in LDS per block
#define QP     4                  // query points per thread

__global__ __launch_bounds__(256) void init_pack_kernel(
    const float* __restrict__ pred, const float* __restrict__ gt,
    float4* __restrict__ packed, unsigned int* __restrict__ minbits,
    float* __restrict__ out) {
  int i = blockIdx.x * 256 + threadIdx.x;         // 0 .. 65535
  minbits[i] = 0x7F800000u;                       // +inf
  const float* src = (i < TOTAL) ? pred : gt;
  int j = (i < TOTAL) ? i : i - TOTAL;
  float x = src[3 * j], y = src[3 * j + 1], z = src[3 * j + 2];
  packed[i] = make_float4(x, y, z, x * x + y * y + z * z);
  if (i == 0) out[0] = 0.f;
}

__global__ __launch_bounds__(256) void chamfer_kernel(
    const float4* __restrict__ packed, unsigned int* __restrict__ minbits) {
  __shared__ float4 tgt[TT];
  int bid = blockIdx.x;
  int tc  = bid & 7;          // target chunk  [0,8)
  int qc  = (bid >> 3) & 7;   // query chunk   [0,8)
  int b   = (bid >> 6) & 3;   // batch         [0,4)
  int dir = bid >> 8;         // 0: q=pred t=gt ; 1: q=gt t=pred

  const float4* qbase = packed + (dir ? TOTAL : 0) + b * NPTS + qc * (256 * QP);
  const float4* tbase = packed + (dir ? 0 : TOTAL) + b * NPTS + tc * TT;
  int t = threadIdx.x;

  // stage target chunk into LDS (coalesced float4 loads)
  #pragma unroll
  for (int k = 0; k < TT / 256; ++k) tgt[t + 256 * k] = tbase[t + 256 * k];
  __syncthreads();

  // query points in registers, pre-scaled by -2
  float qx[QP], qy[QP], qz[QP], sq[QP], m[QP];
  #pragma unroll
  for (int q = 0; q < QP; ++q) {
    float4 v = qbase[t + 256 * q];
    qx[q] = -2.f * v.x; qy[q] = -2.f * v.y; qz[q] = -2.f * v.z;
    sq[q] = v.w; m[q] = INFINITY;
  }

  // inner loop: 1 broadcast ds_read_b128 amortized over QP*4 VALU ops
  #pragma unroll 4
  for (int j = 0; j < TT; ++j) {
    float4 g = tgt[j];
    #pragma unroll
    for (int q = 0; q < QP; ++q) {
      float d = fmaf(qx[q], g.x, g.w);   // s_g - 2 q.g (partial)
      d = fmaf(qy[q], g.y, d);
      d = fmaf(qz[q], g.z, d);
      m[q] = fminf(m[q], d);
    }
  }

  unsigned int* mb = minbits + dir * TOTAL + b * NPTS + qc * (256 * QP);
  #pragma unroll
  for (int q = 0; q < QP; ++q) {
    float v = fmaxf(sq[q] + m[q], 0.f);  // full squared distance, >= 0
    atomicMin(&mb[t + 256 * q], __float_as_uint(v));
  }
}

__global__ __launch_bounds__(256) void reduce_kernel(
    const unsigned int* __restrict__ minbits, float* __restrict__ out) {
  int i = blockIdx.x * 256 + threadIdx.x;
  float v = __uint_as_float(minbits[i]) * (1.0f / 32768.0f);
  #pragma unroll
  for (int off = 32; off > 0; off >>= 1) v += __shfl_down(v, off, 64);
  if ((threadIdx.x & 63) == 0) atomicAdd(out, v);
}

extern "C" void kernel_launch(void* const* d_in, const int* in_sizes, int n_in,
                              void* d_out, int out_size, void* d_ws, size_t ws_size,
                              hipStream_t stream) {
  const float* pred = (const float*)d_in[0];
  const float* gt   = (const float*)d_in[1];
  float* out = (float*)d_out;

  // ws layout: [0, 1MB) packed float4 x 65536 ; [1MB, 1.25MB) minbits x 65536
  float4* packed = (float4*)d_ws;
  unsigned int* minbits = (unsigned int*)((char*)d_ws + 2 * TOTAL * sizeof(float4));

  init_pack_kernel<<<(2 * TOTAL) / 256, 256, 0, stream>>>(pred, gt, packed, minbits, out);
  chamfer_kernel<<<512, 256, 0, stream>>>(packed, minbits);
  reduce_kernel<<<(2 * TOTAL) / 256, 256, 0, stream>>>(minbits, out);
}

// Round 2
// 99.915 us; speedup vs baseline: 1.1996x; 1.1996x over previous
//
#include <hip/hip_runtime.h>
#include <math.h>

// Chamfer distance: pred (4,8192,3) fp32, gt (4,8192,3) fp32 -> scalar fp32.
// dist = s_q + (s_g - 2 q.g); per pair of targets: 6 fma + 1 min3 = 3.5 VALU/pair.
// Each block: 2048 queries (8/thread in regs) x 512-target LDS chunk.
// No atomics in chamfer: per-(query, target-chunk) partial minima in ws,
// combined + summed by a small second kernel (64 block-level atomicAdds).

#define NPTS     8192
#define NB       4
#define NQ_TOTAL 65536            // 2 dirs * 4 batches * 8192 queries
#define TT       512              // targets staged in LDS per block
#define NTC      16               // target chunks
#define QP       8                // query points per thread
#define QCHUNK   (256 * QP)       // 2048 queries per block

__global__ __launch_bounds__(256) void chamfer_kernel(
    const float* __restrict__ pred, const float* __restrict__ gt,
    float* __restrict__ partial, float* __restrict__ out) {
  __shared__ float4 tgt[TT];
  int bid = blockIdx.x;
  int tc  = bid & 15;          // target chunk  [0,16)
  int qc  = (bid >> 4) & 3;    // query chunk   [0,4)
  int b   = (bid >> 6) & 3;    // batch         [0,4)
  int dir = bid >> 8;          // 0: q=pred t=gt ; 1: q=gt t=pred
  const float* qsrc = dir ? gt : pred;
  const float* tsrc = dir ? pred : gt;
  int t = threadIdx.x;
  if (bid == 0 && t == 0) out[0] = 0.f;   // reduce runs after, ordering safe

  // stage + pack target chunk: float3 -> float4(x,y,z,|g|^2)
  const float* tb = tsrc + (size_t)(b * NPTS + tc * TT) * 3;
  for (int k = t; k < TT; k += 256) {
    float x = tb[3 * k], y = tb[3 * k + 1], z = tb[3 * k + 2];
    tgt[k] = make_float4(x, y, z, x * x + y * y + z * z);
  }

  // 8 query points per thread in registers, pre-scaled by -2
  const float* qb = qsrc + (size_t)(b * NPTS + qc * QCHUNK) * 3;
  float qx[QP], qy[QP], qz[QP], sq[QP], m[QP];
  #pragma unroll
  for (int q = 0; q < QP; ++q) {
    int idx = t + 256 * q;
    float x = qb[3 * idx], y = qb[3 * idx + 1], z = qb[3 * idx + 2];
    qx[q] = -2.f * x; qy[q] = -2.f * y; qz[q] = -2.f * z;
    sq[q] = x * x + y * y + z * z;
    m[q] = INFINITY;
  }
  __syncthreads();

  // inner loop: 2 broadcast ds_read_b128 per 2 targets, 7 VALU per 2 pairs per q
  #pragma unroll 2
  for (int j = 0; j < TT; j += 2) {
    float4 g0 = tgt[j], g1 = tgt[j + 1];
    #pragma unroll
    for (int q = 0; q < QP; ++q) {
      float d0 = fmaf(qx[q], g0.x, g0.w);
      d0 = fmaf(qy[q], g0.y, d0);
      d0 = fmaf(qz[q], g0.z, d0);
      float d1 = fmaf(qx[q], g1.x, g1.w);
      d1 = fmaf(qy[q], g1.y, d1);
      d1 = fmaf(qz[q], g1.z, d1);
      m[q] = fminf(m[q], fminf(d0, d1));   // -> v_min3_f32
    }
  }

  // write per-chunk partial minima (full squared distance, clamped >= 0)
  float* pb = partial + (size_t)tc * NQ_TOTAL + dir * 32768 + b * NPTS + qc * QCHUNK;
  #pragma unroll
  for (int q = 0; q < QP; ++q)
    pb[t + 256 * q] = fmaxf(sq[q] + m[q], 0.f);
}

__global__ __launch_bounds__(256) void reduce_kernel(
    const float* __restrict__ partial, float* __restrict__ out) {
  __shared__ float wsum[4];
  float acc = 0.f;
  for (int i = blockIdx.x * 256 + threadIdx.x; i < NQ_TOTAL; i += 64 * 256) {
    float m = partial[i];
    #pragma unroll
    for (int tc = 1; tc < NTC; ++tc)
      m = fminf(m, partial[(size_t)tc * NQ_TOTAL + i]);
    acc += m;
  }
  acc *= (1.0f / 32768.0f);
  #pragma unroll
  for (int off = 32; off > 0; off >>= 1) acc += __shfl_down(acc, off, 64);
  int wid = threadIdx.x >> 6;
  if ((threadIdx.x & 63) == 0) wsum[wid] = acc;
  __syncthreads();
  if (threadIdx.x == 0) atomicAdd(out, wsum[0] + wsum[1] + wsum[2] + wsum[3]);
}

extern "C" void kernel_launch(void* const* d_in, const int* in_sizes, int n_in,
                              void* d_out, int out_size, void* d_ws, size_t ws_size,
                              hipStream_t stream) {
  const float* pred = (const float*)d_in[0];
  const float* gt   = (const float*)d_in[1];
  float* out = (float*)d_out;
  float* partial = (float*)d_ws;   // 16 * 65536 * 4 B = 4 MB

  chamfer_kernel<<<512, 256, 0, stream>>>(pred, gt, partial, out);
  reduce_kernel<<<64, 256, 0, stream>>>(partial, out);
}